// Round 14
// baseline (53.676 us; speedup 1.0000x reference)
//
#include <hip/hip_runtime.h>
#include <math.h>

#define LQ 256
#define MEML 256
#define LK 512
#define BB 4
#define NH 8
#define DM 128

#define IT 8                  // i-tile per score block (20 KB LDS)
#define QSTRIDE 20            // LDS q row stride (floats): 80B, 16B-aligned

constexpr float INV2PI = 0.15915494309189535f;

// ---------------------------------------------------------------------------
// Projection (identical to R11/R12), pre-scaled by paramR[h]/(2*pi):
//   qs[(i*4+b)*128 + h*16+d]
//   ksT[((d>>2)*512 + j)*128 + (b*8+h)*4 + (d&3)]
// ---------------------------------------------------------------------------
__global__ __launch_bounds__(128) void proj_kernel(
    const float* __restrict__ hh, const float* __restrict__ mems,
    const float* __restrict__ Wq, const float* __restrict__ Wk,
    const float* __restrict__ paramR,
    float* __restrict__ qs, float* __restrict__ ksT)
{
    __shared__ float x[8 * 128];
    const int blk = blockIdx.x;
    const int t = threadIdx.x;
    const bool isQ = (blk < 128);                 // 128 q-blocks, 256 k-blocks
    const int row0 = isQ ? blk * 8 : (blk - 128) * 8;
    const float* __restrict__ W = isQ ? Wq : Wk;

    for (int r = 0; r < 8; ++r) {
        const int row = row0 + r;
        const float* src = isQ ? (hh + row * DM)
                               : ((row < MEML * BB) ? (mems + row * DM)
                                                    : (hh + (row - MEML * BB) * DM));
        x[r * 128 + t] = src[t];
    }
    __syncthreads();

    float acc[8] = {0, 0, 0, 0, 0, 0, 0, 0};
    const float* wrow = W + t * DM;
    for (int k = 0; k < DM; k += 4) {
        const float4 w = *(const float4*)(wrow + k);
        #pragma unroll
        for (int r = 0; r < 8; ++r) {
            acc[r] += x[r * 128 + k + 0] * w.x + x[r * 128 + k + 1] * w.y
                    + x[r * 128 + k + 2] * w.z + x[r * 128 + k + 3] * w.w;
        }
    }
    const int h = t >> 4, d = t & 15;
    const float rs = paramR[h] * INV2PI;
    if (isQ) {
        float* dst = qs + row0 * 128 + t;
        #pragma unroll
        for (int r = 0; r < 8; ++r) dst[r * 128] = acc[r] * rs;
    } else {
        #pragma unroll
        for (int r = 0; r < 8; ++r) {
            const int row = row0 + r;
            const int j = row >> 2, b = row & 3;
            ksT[((d >> 2) * LK + j) * 128 + (b * 8 + h) * 4 + (d & 3)] = acc[r] * rs;
        }
    }
}

// ---------------------------------------------------------------------------
// Score PROBE at PRODUCTION config (R12 exactly: IT=8, 256 thr, lb(256,8),
// grid 32x64): chain replicated 3x (opaque asm blocks CSE; exact fmaxf
// merge). Purpose: surface score above the ~43us fill dispatches so its
// steady-state VALUBusy/Occupancy/FETCH appear, adjudicating the ~10us
// stall at THIS config. dur prediction ~53us.
// ---------------------------------------------------------------------------
__global__ __launch_bounds__(256, 8) void score_kernel(
    const float* __restrict__ qs, const float* __restrict__ ksT,
    float* __restrict__ out)
{
    __shared__ float qt[IT * 32 * QSTRIDE];       // 20480 B
    const int t = threadIdx.x;
    const int bh = t & 31;
    const int js = t >> 5;                        // 0..7
    const int key = bh >> 3;                      // 0..3 chunk-permutation key
    const int i0 = blockIdx.x * IT;               // 32 i-tiles
    const int j = blockIdx.y * 8 + js;            // 64 j-tiles of 8

    constexpr float i2 = INV2PI * INV2PI;
    constexpr float i4 = i2 * i2;
    constexpr float i8 = i4 * i4;
    constexpr float C16 = i8 * i8;                // (2pi)^-16
    constexpr float EPS = 2.0e-4f * INV2PI;       // 3.18e-5 rev; EPS^8 > FLT_MIN

    {
        const float* src = qs + i0 * 32 * 16;
        #pragma unroll
        for (int rep = 0; rep < 4; ++rep) {
            const int c4 = rep * 256 + t;         // float4 chunk id, 0..1023
            const int row = c4 >> 2, cc = (c4 & 3) * 4;
            const float4 v = *(const float4*)(src + c4 * 4);
            *(float4*)(&qt[row * QSTRIDE + cc]) = v;
        }
    }

    float k[16];
    #pragma unroll
    for (int s = 0; s < 4; ++s) {
        const int plane = s ^ key;
        const float4 v = *(const float4*)(ksT + (plane * LK + j) * 128 + bh * 4);
        k[s * 4 + 0] = v.x; k[s * 4 + 1] = v.y;
        k[s * 4 + 2] = v.z; k[s * 4 + 3] = v.w;
    }
    __syncthreads();

    #pragma unroll 4
    for (int ii = 0; ii < IT; ++ii) {
        const float* qrow = &qt[(ii * 32 + bh) * QSTRIDE];
        float q[16];
        #pragma unroll
        for (int s = 0; s < 4; ++s) {
            const float4 v = *(const float4*)(qrow + ((s ^ key) << 2));
            q[s * 4 + 0] = v.x; q[s * 4 + 1] = v.y;
            q[s * 4 + 2] = v.z; q[s * 4 + 3] = v.w;
        }
        float rr[3];
        #pragma unroll
        for (int rep = 0; rep < 3; ++rep) {
            float pn0 = 1.f, pd0 = 1.f, pn1 = 1.f, pd1 = 1.f;
            #pragma unroll
            for (int d = 0; d < 16; ++d) {
                float u = q[d] - k[d];
                asm volatile("" : "+v"(u));       // opaque: blocks cross-rep CSE
                const float u2 = fmaxf(__builtin_fabsf(u), EPS);
                const float s = __builtin_amdgcn_sinf(u2);   // sin(2pi*u2)
                if (d < 8) { pn0 *= s; pd0 *= u2; }
                else       { pn1 *= s; pd1 *= u2; }
            }
            rr[rep] = __builtin_fabsf(pn0 * __builtin_amdgcn_rcpf(pd0)
                                    * pn1 * __builtin_amdgcn_rcpf(pd1)) * C16;
        }
        out[((i0 + ii) * LK + j) * 32 + bh] =
            fmaxf(fmaxf(rr[0], rr[1]), rr[2]);    // bit-identical values
    }
}

extern "C" void kernel_launch(void* const* d_in, const int* in_sizes, int n_in,
                              void* d_out, int out_size, void* d_ws, size_t ws_size,
                              hipStream_t stream) {
    const float* hh     = (const float*)d_in[0];
    const float* mems   = (const float*)d_in[1];
    const float* Wq     = (const float*)d_in[2];
    const float* Wk     = (const float*)d_in[3];
    const float* paramR = (const float*)d_in[4];
    float* out = (float*)d_out;

    float* qs  = (float*)d_ws;                // 131072 floats
    float* ksT = qs + LQ * BB * DM;           // 262144 floats

    proj_kernel<<<384, 128, 0, stream>>>(hh, mems, Wq, Wk, paramR, qs, ksT);
    score_kernel<<<dim3(LQ / IT, LK / 8), 256, 0, stream>>>(qs, ksT, out);
}

// Round 15
// 34.280 us; speedup vs baseline: 1.5658x; 1.5658x over previous
//
#include <hip/hip_runtime.h>
#include <math.h>

#define LQ 256
#define MEML 256
#define LK 512
#define BB 4
#define NH 8
#define DM 128

#define IT 4                  // i-tile per score block; grid 64x64 = 4096 blocks

constexpr float INV2PI = 0.15915494309189535f;

// ---------------------------------------------------------------------------
// Projection, pre-scaled by paramR[h]/(2*pi). BOTH outputs plane-major so
// score loads are 512B-contiguous per 32-lane group:
//   qsP[((d>>2)*256 + i)*128 + (b*8+h)*4 + (d&3)]
//   ksT[((d>>2)*512 + j)*128 + (b*8+h)*4 + (d&3)]
// ---------------------------------------------------------------------------
__global__ __launch_bounds__(128) void proj_kernel(
    const float* __restrict__ hh, const float* __restrict__ mems,
    const float* __restrict__ Wq, const float* __restrict__ Wk,
    const float* __restrict__ paramR,
    float* __restrict__ qsP, float* __restrict__ ksT)
{
    __shared__ float x[8 * 128];
    const int blk = blockIdx.x;
    const int t = threadIdx.x;
    const bool isQ = (blk < 128);                 // 128 q-blocks, 256 k-blocks
    const int row0 = isQ ? blk * 8 : (blk - 128) * 8;
    const float* __restrict__ W = isQ ? Wq : Wk;

    for (int r = 0; r < 8; ++r) {
        const int row = row0 + r;
        const float* src = isQ ? (hh + row * DM)
                               : ((row < MEML * BB) ? (mems + row * DM)
                                                    : (hh + (row - MEML * BB) * DM));
        x[r * 128 + t] = src[t];
    }
    __syncthreads();

    float acc[8] = {0, 0, 0, 0, 0, 0, 0, 0};
    const float* wrow = W + t * DM;
    for (int k = 0; k < DM; k += 4) {
        const float4 w = *(const float4*)(wrow + k);
        #pragma unroll
        for (int r = 0; r < 8; ++r) {
            acc[r] += x[r * 128 + k + 0] * w.x + x[r * 128 + k + 1] * w.y
                    + x[r * 128 + k + 2] * w.z + x[r * 128 + k + 3] * w.w;
        }
    }
    const int h = t >> 4, d = t & 15;
    const float rs = paramR[h] * INV2PI;
    #pragma unroll
    for (int r = 0; r < 8; ++r) {
        const int row = row0 + r;
        const int b = row & 3;
        const float v = acc[r] * rs;
        if (isQ) {
            const int i = row >> 2;
            qsP[((d >> 2) * LQ + i) * 128 + (b * 8 + h) * 4 + (d & 3)] = v;
        } else {
            const int j = row >> 2;
            ksT[((d >> 2) * LK + j) * 128 + (b * 8 + h) * 4 + (d & 3)] = v;
        }
    }
}

// ---------------------------------------------------------------------------
// Score, ZERO LDS / ZERO barriers: k[16] VGPR-resident (one coalesced load);
// q streamed per-ii straight from L2 (4 float4, 512B-contiguous per 32-lane
// group; ~64MB total @ L2 BW ~ 2us). IT=4, grid 4096 = 2 block generations
// per CU so ramp/tail overlap. lb(256,8): 8 blocks/CU, VGPR<=64.
// ---------------------------------------------------------------------------
__global__ __launch_bounds__(256, 8) void score_kernel(
    const float* __restrict__ qsP, const float* __restrict__ ksT,
    float* __restrict__ out)
{
    const int t = threadIdx.x;
    const int bh = t & 31;
    const int js = t >> 5;                        // 0..7
    const int i0 = blockIdx.x * IT;               // 64 i-tiles
    const int j = blockIdx.y * 8 + js;            // 64 j-tiles of 8

    constexpr float i2 = INV2PI * INV2PI;
    constexpr float i4 = i2 * i2;
    constexpr float i8 = i4 * i4;
    constexpr float C16 = i8 * i8;                // (2pi)^-16
    constexpr float EPS = 2.0e-4f * INV2PI;       // 3.18e-5 rev; EPS^8 > FLT_MIN

    float k[16];
    #pragma unroll
    for (int s = 0; s < 4; ++s) {
        const float4 v = *(const float4*)(ksT + (s * LK + j) * 128 + bh * 4);
        k[s * 4 + 0] = v.x; k[s * 4 + 1] = v.y;
        k[s * 4 + 2] = v.z; k[s * 4 + 3] = v.w;
    }

    #pragma unroll 2
    for (int ii = 0; ii < IT; ++ii) {
        const int i = i0 + ii;
        float4 qv[4];
        #pragma unroll
        for (int s = 0; s < 4; ++s)
            qv[s] = *(const float4*)(qsP + (s * LQ + i) * 128 + bh * 4);

        float pn0 = 1.f, pd0 = 1.f, pn1 = 1.f, pd1 = 1.f;
        #pragma unroll
        for (int s = 0; s < 4; ++s) {
            const float qq[4] = {qv[s].x, qv[s].y, qv[s].z, qv[s].w};
            #pragma unroll
            for (int dd = 0; dd < 4; ++dd) {
                const float u2 = fmaxf(__builtin_fabsf(qq[dd] - k[s * 4 + dd]), EPS);
                const float sn = __builtin_amdgcn_sinf(u2);  // sin(2pi*u2)
                if (s < 2) { pn0 *= sn; pd0 *= u2; }
                else       { pn1 *= sn; pd1 *= u2; }
            }
        }
        const float r0 = pn0 * __builtin_amdgcn_rcpf(pd0);
        const float r1 = pn1 * __builtin_amdgcn_rcpf(pd1);
        out[(i * LK + j) * 32 + bh] = __builtin_fabsf(r0 * r1) * C16;
    }
}

extern "C" void kernel_launch(void* const* d_in, const int* in_sizes, int n_in,
                              void* d_out, int out_size, void* d_ws, size_t ws_size,
                              hipStream_t stream) {
    const float* hh     = (const float*)d_in[0];
    const float* mems   = (const float*)d_in[1];
    const float* Wq     = (const float*)d_in[2];
    const float* Wk     = (const float*)d_in[3];
    const float* paramR = (const float*)d_in[4];
    float* out = (float*)d_out;

    float* qsP = (float*)d_ws;                // 131072 floats
    float* ksT = qsP + LQ * BB * DM;          // 262144 floats

    proj_kernel<<<384, 128, 0, stream>>>(hh, mems, Wq, Wk, paramR, qsP, ksT);
    score_kernel<<<dim3(LQ / IT, LK / 8), 256, 0, stream>>>(qsP, ksT, out);
}

// Round 16
// 30.730 us; speedup vs baseline: 1.7467x; 1.1155x over previous
//
#include <hip/hip_runtime.h>
#include <math.h>

#define LQ 256
#define MEML 256
#define LK 512
#define BB 4
#define NH 8
#define DM 128

#define IT 8                  // i-tile per score block (20 KB LDS)
#define QSTRIDE 20            // LDS q row stride (floats): 80B, 16B-aligned

constexpr float INV2PI = 0.15915494309189535f;

// ---------------------------------------------------------------------------
// Projection (identical to R11/R12), pre-scaled by paramR[h]/(2*pi):
//   qs[(i*4+b)*128 + h*16+d]
//   ksT[((d>>2)*512 + j)*128 + (b*8+h)*4 + (d&3)]
// ---------------------------------------------------------------------------
__global__ __launch_bounds__(128) void proj_kernel(
    const float* __restrict__ hh, const float* __restrict__ mems,
    const float* __restrict__ Wq, const float* __restrict__ Wk,
    const float* __restrict__ paramR,
    float* __restrict__ qs, float* __restrict__ ksT)
{
    __shared__ float x[8 * 128];
    const int blk = blockIdx.x;
    const int t = threadIdx.x;
    const bool isQ = (blk < 128);                 // 128 q-blocks, 256 k-blocks
    const int row0 = isQ ? blk * 8 : (blk - 128) * 8;
    const float* __restrict__ W = isQ ? Wq : Wk;

    for (int r = 0; r < 8; ++r) {
        const int row = row0 + r;
        const float* src = isQ ? (hh + row * DM)
                               : ((row < MEML * BB) ? (mems + row * DM)
                                                    : (hh + (row - MEML * BB) * DM));
        x[r * 128 + t] = src[t];
    }
    __syncthreads();

    float acc[8] = {0, 0, 0, 0, 0, 0, 0, 0};
    const float* wrow = W + t * DM;
    for (int k = 0; k < DM; k += 4) {
        const float4 w = *(const float4*)(wrow + k);
        #pragma unroll
        for (int r = 0; r < 8; ++r) {
            acc[r] += x[r * 128 + k + 0] * w.x + x[r * 128 + k + 1] * w.y
                    + x[r * 128 + k + 2] * w.z + x[r * 128 + k + 3] * w.w;
        }
    }
    const int h = t >> 4, d = t & 15;
    const float rs = paramR[h] * INV2PI;
    if (isQ) {
        float* dst = qs + row0 * 128 + t;
        #pragma unroll
        for (int r = 0; r < 8; ++r) dst[r * 128] = acc[r] * rs;
    } else {
        #pragma unroll
        for (int r = 0; r < 8; ++r) {
            const int row = row0 + r;
            const int j = row >> 2, b = row & 3;
            ksT[((d >> 2) * LK + j) * 128 + (b * 8 + h) * 4 + (d & 3)] = acc[r] * rs;
        }
    }
}

// ---------------------------------------------------------------------------
// Score with FORCED 2-way ILP: two i's processed simultaneously as
// hand-interleaved straight-line code (two q reg-sets, two independent
// sin-product chains sharing one k). R14 showed the compiler serialized the
// pragma-unroll at VGPR=32; this makes the second chain unavoidable.
// lb(256,6): VGPR cap ~85 (need ~70), 6 blocks/CU.
// ---------------------------------------------------------------------------
__global__ __launch_bounds__(256, 6) void score_kernel(
    const float* __restrict__ qs, const float* __restrict__ ksT,
    float* __restrict__ out)
{
    __shared__ float qt[IT * 32 * QSTRIDE];       // 20480 B
    const int t = threadIdx.x;
    const int bh = t & 31;
    const int js = t >> 5;                        // 0..7
    const int key = bh >> 3;                      // 0..3 chunk-permutation key
    const int i0 = blockIdx.x * IT;               // 32 i-tiles
    const int j = blockIdx.y * 8 + js;            // 64 j-tiles of 8

    constexpr float i2 = INV2PI * INV2PI;
    constexpr float i4 = i2 * i2;
    constexpr float i8 = i4 * i4;
    constexpr float C16 = i8 * i8;                // (2pi)^-16
    constexpr float EPS = 2.0e-4f * INV2PI;       // 3.18e-5 rev; EPS^8 > FLT_MIN

    // stage q-tile (as R12)
    {
        const float* src = qs + i0 * 32 * 16;
        #pragma unroll
        for (int rep = 0; rep < 4; ++rep) {
            const int c4 = rep * 256 + t;         // float4 chunk id, 0..1023
            const int row = c4 >> 2, cc = (c4 & 3) * 4;
            const float4 v = *(const float4*)(src + c4 * 4);
            *(float4*)(&qt[row * QSTRIDE + cc]) = v;
        }
    }

    // k resident, chunk-permuted to match swizzled q reads
    float k[16];
    #pragma unroll
    for (int s = 0; s < 4; ++s) {
        const int plane = s ^ key;
        const float4 v = *(const float4*)(ksT + (plane * LK + j) * 128 + bh * 4);
        k[s * 4 + 0] = v.x; k[s * 4 + 1] = v.y;
        k[s * 4 + 2] = v.z; k[s * 4 + 3] = v.w;
    }
    __syncthreads();

    #pragma unroll
    for (int ii = 0; ii < IT; ii += 2) {
        const float* qrowA = &qt[((ii + 0) * 32 + bh) * QSTRIDE];
        const float* qrowB = &qt[((ii + 1) * 32 + bh) * QSTRIDE];
        float qa[16], qb[16];
        #pragma unroll
        for (int s = 0; s < 4; ++s) {
            const int sw = (s ^ key) << 2;
            const float4 a = *(const float4*)(qrowA + sw);
            const float4 b = *(const float4*)(qrowB + sw);
            qa[s * 4 + 0] = a.x; qa[s * 4 + 1] = a.y;
            qa[s * 4 + 2] = a.z; qa[s * 4 + 3] = a.w;
            qb[s * 4 + 0] = b.x; qb[s * 4 + 1] = b.y;
            qb[s * 4 + 2] = b.z; qb[s * 4 + 3] = b.w;
        }
        float pnA0 = 1.f, pdA0 = 1.f, pnA1 = 1.f, pdA1 = 1.f;
        float pnB0 = 1.f, pdB0 = 1.f, pnB1 = 1.f, pdB1 = 1.f;
        #pragma unroll
        for (int d = 0; d < 16; ++d) {
            const float uA = fmaxf(__builtin_fabsf(qa[d] - k[d]), EPS);
            const float uB = fmaxf(__builtin_fabsf(qb[d] - k[d]), EPS);
            const float sA = __builtin_amdgcn_sinf(uA);  // sin(2pi*u)
            const float sB = __builtin_amdgcn_sinf(uB);
            if (d < 8) { pnA0 *= sA; pdA0 *= uA; pnB0 *= sB; pdB0 *= uB; }
            else       { pnA1 *= sA; pdA1 *= uA; pnB1 *= sB; pdB1 *= uB; }
        }
        const float rA0 = pnA0 * __builtin_amdgcn_rcpf(pdA0);
        const float rA1 = pnA1 * __builtin_amdgcn_rcpf(pdA1);
        const float rB0 = pnB0 * __builtin_amdgcn_rcpf(pdB0);
        const float rB1 = pnB1 * __builtin_amdgcn_rcpf(pdB1);
        out[((i0 + ii + 0) * LK + j) * 32 + bh] = __builtin_fabsf(rA0 * rA1) * C16;
        out[((i0 + ii + 1) * LK + j) * 32 + bh] = __builtin_fabsf(rB0 * rB1) * C16;
    }
}

extern "C" void kernel_launch(void* const* d_in, const int* in_sizes, int n_in,
                              void* d_out, int out_size, void* d_ws, size_t ws_size,
                              hipStream_t stream) {
    const float* hh     = (const float*)d_in[0];
    const float* mems   = (const float*)d_in[1];
    const float* Wq     = (const float*)d_in[2];
    const float* Wk     = (const float*)d_in[3];
    const float* paramR = (const float*)d_in[4];
    float* out = (float*)d_out;

    float* qs  = (float*)d_ws;                // 131072 floats
    float* ksT = qs + LQ * BB * DM;           // 262144 floats

    proj_kernel<<<384, 128, 0, stream>>>(hh, mems, Wq, Wk, paramR, qs, ksT);
    score_kernel<<<dim3(LQ / IT, LK / 8), 256, 0, stream>>>(qs, ksT, out);
}